// Round 4
// baseline (822.101 us; speedup 1.0000x reference)
//
#include <hip/hip_runtime.h>
#include <hip/hip_bf16.h>
#include <cstdint>

#define DEVINL __device__ __forceinline__

using bf16 = __hip_bfloat16;
typedef __bf16 bf16x8 __attribute__((ext_vector_type(8)));
typedef float f32x4 __attribute__((ext_vector_type(4)));
typedef unsigned short u16x8 __attribute__((ext_vector_type(8)));

static constexpr int MTOK = 131072;  // B*N tokens

DEVINL void async_ld16(const void* g, void* l) {
  __builtin_amdgcn_global_load_lds(
      (__attribute__((address_space(1))) void*)(g),
      (__attribute__((address_space(3))) void*)(l), 16, 0, 0);
}

DEVINL unsigned short bfbits(float v) {
  bf16 h = __float2bfloat16(v);
  return *reinterpret_cast<unsigned short*>(&h);
}

// Swizzle-packed panel layout for [rows x K] bf16 matrices:
// granule(16B) f = row*8 + (chunk ^ (row&7)), panels of 128x64 linear.
DEVINL long pkaddr(long m, int k, int KP) {
  const long tile = m >> 7;
  const int row = (int)(m & 127);
  const int panel = k >> 6;
  const int c8 = ((k & 63) >> 3) ^ (row & 7);
  return ((tile * KP + panel) * 1024 + row * 8 + c8) * 8 + (k & 7);
}

// ---------------- deferred weights fp32 -> packed bf16 ----------------------
// w1 packed KP=4 (8 row-tiles of 128 hidden units x K=256);
// w2 packed KP=16 (2 row-tiles of 128 j x K=1024).
__global__ __launch_bounds__(256) void cvt_w2(
    const float* __restrict__ ow, const float* __restrict__ w1,
    const float* __restrict__ w2, bf16* __restrict__ out) {
  int i = blockIdx.x * 256 + threadIdx.x;
  float v; long base; int n, k, KP;
  if (i < 65536)        { v = ow[i]; base = 0;      n = i >> 8;  k = i & 255;  KP = 4; }
  else if (i < 327680)  { int j = i - 65536;  v = w1[j]; base = 65536;  n = j >> 8;  k = j & 255;  KP = 4; }
  else                  { int j = i - 327680; v = w2[j]; base = 327680; n = j >> 10; k = j & 1023; KP = 16; }
  out[base + pkaddr(n, k, KP)] = __float2bfloat16(v);
}

// ---------------- LayerNorm (+optional window partition), fp32 -> packed ----
template <bool REMAP>
__global__ __launch_bounds__(256) void ln_kern(
    const float* __restrict__ x, const float* __restrict__ gw,
    const float* __restrict__ bw, bf16* __restrict__ out) {
  const int lane = threadIdx.x & 63;
  const int wv = threadIdx.x >> 6;
  const long tok = (long)blockIdx.x * 4 + wv;
  const float4 v = *(const float4*)(x + tok * 256 + lane * 4);
  float s = v.x + v.y + v.z + v.w;
#pragma unroll
  for (int off = 32; off > 0; off >>= 1) s += __shfl_xor(s, off);
  const float mean = s * (1.0f / 256.0f);
  const float dx = v.x - mean, dy = v.y - mean, dz = v.z - mean, dw = v.w - mean;
  float q = dx * dx + dy * dy + dz * dz + dw * dw;
#pragma unroll
  for (int off = 32; off > 0; off >>= 1) q += __shfl_xor(q, off);
  const float inv = rsqrtf(q * (1.0f / 256.0f) + 1e-5f);
  long m;
  if (REMAP) {
    const int b = (int)(tok >> 14);
    const int n = (int)(tok & 16383);
    const int row = n >> 7, col = n & 127;
    const int w = b * 256 + (row >> 3) * 16 + (col >> 3);
    const int t = (row & 7) * 8 + (col & 7);
    m = (long)w * 64 + t;
  } else {
    m = tok;
  }
  const float4 g = *(const float4*)(gw + lane * 4);
  const float4 bb = *(const float4*)(bw + lane * 4);
  ushort4 o;
  o.x = bfbits(dx * inv * g.x + bb.x);
  o.y = bfbits(dy * inv * g.y + bb.y);
  o.z = bfbits(dz * inv * g.z + bb.z);
  o.w = bfbits(dw * inv * g.w + bb.w);
  *(ushort4*)((unsigned short*)out + pkaddr(m, lane * 4, 4)) = o;
}

// ---------------- GEMM: C = A @ B^T (packed A, packed/fp32 B, +epilogue) ----
enum { EPI_QKV = 0, EPI_OUTPROJ = 1, EPI_GELU = 2, EPI_RESID = 3 };

template <int KP, int EPI, bool BF32>
__global__ __launch_bounds__(256) void gemm_db(
    const bf16* __restrict__ A, const void* __restrict__ Bw,
    const float* __restrict__ bias,
    bf16* __restrict__ oQ, bf16* __restrict__ oK, bf16* __restrict__ oV,
    const float* __restrict__ resid, float* __restrict__ of32,
    bf16* __restrict__ obf) {
  __shared__ __align__(16) unsigned short smem[32768];  // 64 KiB
  const int tid = threadIdx.x;
  const int lane = tid & 63, wv = tid >> 6;
  const int quad = lane >> 4, l16 = lane & 15;
  const int wm = wv >> 1, wn = wv & 1;
  // T1 XCD-chunked swizzle (bijective; nwg divisible by 8)
  const int gx = gridDim.x;
  const int nwg = gx * gridDim.y;
  const int orig = blockIdx.x + gx * blockIdx.y;
  const int wg = (orig & 7) * (nwg >> 3) + (orig >> 3);
  const int ntile = wg % gx;
  const long mtile = wg / gx;
  const long m0 = mtile * 128;
  const int n0 = ntile * 128;

  const bf16* Bp = (const bf16*)Bw;
  const float* Bf = (const float*)Bw;
  float4 br[4][2];

  auto stageA = [&](int i, int buf) {
    const bf16* Apan = A + (mtile * KP + i) * 8192;
#pragma unroll
    for (int p = 0; p < 4; ++p) {
      const int f = p * 256 + tid;
      async_ld16(Apan + f * 8, (char*)smem + buf * 16384 + f * 16);
    }
  };
  auto stageB = [&](int i, int buf) {
    const bf16* Bpan = Bp + ((long)ntile * KP + i) * 8192;
#pragma unroll
    for (int p = 0; p < 4; ++p) {
      const int f = p * 256 + tid;
      async_ld16(Bpan + f * 8, (char*)smem + 32768 + buf * 16384 + f * 16);
    }
  };
  auto issueB = [&](int i) {
#pragma unroll
    for (int p = 0; p < 4; ++p) {
      const int f = p * 256 + tid, row = f >> 3;
      const int chunk = (f & 7) ^ (row & 7);
      const float* src = Bf + (long)(n0 + row) * 256 + i * 64 + chunk * 8;
      br[p][0] = *(const float4*)(src);
      br[p][1] = *(const float4*)(src + 4);
    }
  };
  auto writeB = [&](int buf) {
#pragma unroll
    for (int p = 0; p < 4; ++p) {
      const int f = p * 256 + tid;
      u16x8 o;
      o[0] = bfbits(br[p][0].x); o[1] = bfbits(br[p][0].y);
      o[2] = bfbits(br[p][0].z); o[3] = bfbits(br[p][0].w);
      o[4] = bfbits(br[p][1].x); o[5] = bfbits(br[p][1].y);
      o[6] = bfbits(br[p][1].z); o[7] = bfbits(br[p][1].w);
      *(u16x8*)((char*)smem + 32768 + buf * 16384 + f * 16) = o;
    }
  };

  const f32x4 fz = {0.f, 0.f, 0.f, 0.f};
  f32x4 acc[4][4];
#pragma unroll
  for (int a = 0; a < 4; ++a) {
#pragma unroll
    for (int b = 0; b < 4; ++b) acc[a][b] = fz;
  }

  if constexpr (BF32) { issueB(0); stageA(0, 0); }
  else                { stageA(0, 0); stageB(0, 0); }

#pragma unroll 1
  for (int i = 0; i < KP; ++i) {
    if constexpr (BF32) writeB(i & 1);
    __syncthreads();
    if (i + 1 < KP) {
      if constexpr (BF32) { issueB(i + 1); stageA(i + 1, (i + 1) & 1); }
      else                { stageA(i + 1, (i + 1) & 1); stageB(i + 1, (i + 1) & 1); }
    }
    const unsigned short* Asb = smem + (i & 1) * 8192;
    const unsigned short* Bsb = smem + 16384 + (i & 1) * 8192;
#pragma unroll
    for (int kk = 0; kk < 2; ++kk) {
      bf16x8 af[4], bfr[4];
#pragma unroll
      for (int mt = 0; mt < 4; ++mt) {
        const int row = wm * 64 + mt * 16 + l16;
        const int c8 = (kk * 4 + quad) ^ (row & 7);
        af[mt] = *(const bf16x8*)(Asb + row * 64 + c8 * 8);
      }
#pragma unroll
      for (int nt = 0; nt < 4; ++nt) {
        const int row = wn * 64 + nt * 16 + l16;
        const int c8 = (kk * 4 + quad) ^ (row & 7);
        bfr[nt] = *(const bf16x8*)(Bsb + row * 64 + c8 * 8);
      }
#pragma unroll
      for (int mt = 0; mt < 4; ++mt) {
#pragma unroll
        for (int nt = 0; nt < 4; ++nt) {
          acc[mt][nt] = __builtin_amdgcn_mfma_f32_16x16x32_bf16(
              af[mt], bfr[nt], acc[mt][nt], 0, 0, 0);
        }
      }
    }
  }

  // ---- epilogue. C/D layout col=lane&15, row=quad*4+reg [m89-verified] ----
  if constexpr (EPI == EPI_QKV) {
    const int region = n0 >> 8;
    float bj4[4];
#pragma unroll
    for (int nt = 0; nt < 4; ++nt) bj4[nt] = bias[n0 + wn * 64 + nt * 16 + l16];
    __syncthreads();
    if (region < 2) {
#pragma unroll
      for (int mt = 0; mt < 4; ++mt) {
#pragma unroll
        for (int nt = 0; nt < 4; ++nt) {
          const int j_l = wn * 64 + nt * 16 + l16;
#pragma unroll
          for (int r = 0; r < 4; ++r) {
            const int m_l = wm * 64 + mt * 16 + quad * 4 + r;
            smem[m_l * 136 + j_l] = bfbits(acc[mt][nt][r] + bj4[nt]);
          }
        }
      }
    } else {
#pragma unroll
      for (int mt = 0; mt < 4; ++mt) {
#pragma unroll
        for (int nt = 0; nt < 4; ++nt) {
          const int j_l = wn * 64 + nt * 16 + l16;
          const int m_b = wm * 64 + mt * 16 + quad * 4;
          ushort4 pk;
          pk.x = bfbits(acc[mt][nt][0] + bj4[nt]);
          pk.y = bfbits(acc[mt][nt][1] + bj4[nt]);
          pk.z = bfbits(acc[mt][nt][2] + bj4[nt]);
          pk.w = bfbits(acc[mt][nt][3] + bj4[nt]);
          *(ushort4*)(smem + j_l * 136 + m_b) = pk;
        }
      }
    }
    __syncthreads();
    bf16* dst0 = (region == 0) ? oQ : ((region == 1) ? oK : oV);
    const int hbase = (n0 >> 5) & 7;
    const long w0 = m0 >> 6;
    if (region < 2) {
#pragma unroll
      for (int p = 0; p < 8; ++p) {
        const int u = p * 256 + tid;
        const int c = u >> 8, rr = u & 255;
        const int t = rr >> 2, d0 = (rr & 3) * 8;
        const unsigned short* src = smem + ((c >> 2) * 64 + t) * 136 + (c & 3) * 32 + d0;
        const long hb = (w0 + (c >> 2)) * 8 + hbase + (c & 3);
        *(u16x8*)((unsigned short*)dst0 + (hb * 64 + t) * 32 + d0) = *(const u16x8*)src;
      }
    } else {
#pragma unroll
      for (int p = 0; p < 8; ++p) {
        const int u = p * 256 + tid;
        const int c = u >> 8, rr = u & 255;
        const int d = rr >> 3, t0 = (rr & 7) * 8;
        const unsigned short* src = smem + ((c & 3) * 32 + d) * 136 + (c >> 2) * 64 + t0;
        const long hb = (w0 + (c >> 2)) * 8 + hbase + (c & 3);
        *(u16x8*)((unsigned short*)dst0 + (hb * 32 + d) * 64 + t0) = *(const u16x8*)src;
      }
    }
  } else {
    // fp32 epilogues (already 64B-run coalesced)
#pragma unroll
    for (int mt = 0; mt < 4; ++mt) {
#pragma unroll
      for (int nt = 0; nt < 4; ++nt) {
        const long mb = m0 + wm * 64 + mt * 16 + quad * 4;
        const int j = n0 + wn * 64 + nt * 16 + l16;
        const float bj = bias[j];
#pragma unroll
        for (int r = 0; r < 4; ++r) {
          const long m = mb + r;
          const float v = acc[mt][nt][r] + bj;
          if constexpr (EPI == EPI_OUTPROJ) {
            const int w = (int)(m >> 6), t = (int)(m & 63);
            const int b = w >> 8, wi = w & 255;
            const int row = (wi >> 4) * 8 + (t >> 3);
            const int col = (wi & 15) * 8 + (t & 7);
            const long addr = ((long)b * 16384 + row * 128 + col) * 256 + j;
            of32[addr] = v + resid[addr];
          } else {  // EPI_RESID
            const long addr = m * 256 + j;
            of32[addr] += v;
          }
        }
      }
    }
  }
}

// ---------------- fused MLP: out += GELU(A @ W1^T) @ W2^T + b2 --------------
// One block per 128-row m-tile. A tile (128x256 bf16, packed) resident in LDS;
// 8 hidden-chunks of 128: phase1 (swapped operands: C rows = hidden -> P packs
// with ds_write_b64) -> P in LDS (packed A-operand layout) -> phase2
// accumulates the full 128x256 out tile in registers. Weights stream through a
// 16KiB-double-buffer (L2-hot), single-barrier pipeline as in gemm_db.
// LDS: A 64K + Wbuf 32K + Pbuf 32K = 128 KiB -> 1 block/CU, 1 wave/SIMD.
__global__ __launch_bounds__(256, 1) void mlp_fused(
    const bf16* __restrict__ A, const bf16* __restrict__ W1p,
    const bf16* __restrict__ W2p, const float* __restrict__ b1,
    const float* __restrict__ b2, float* __restrict__ out) {
  __shared__ __align__(16) unsigned short smem[65536];  // 128 KiB
  unsigned short* Ares = smem;            // 4 panels (32768)
  unsigned short* Wbuf = smem + 32768;    // 2 x 8192
  unsigned short* Pbuf = smem + 49152;    // 2 x 8192
  const int tid = threadIdx.x;
  const int lane = tid & 63;
  const int wv = tid >> 6;
  const int quad = lane >> 4, l16 = lane & 15;
  const int wm = wv >> 1, wn = wv & 1;
  const long mtile = blockIdx.x;

  auto stageW = [&](const bf16* wp, int buf) {
#pragma unroll
    for (int c = 0; c < 4; ++c) {
      const int f = c * 256 + tid;
      async_ld16(wp + f * 8, (char*)(Wbuf + buf * 8192) + f * 16);
    }
  };
  auto wptr = [&](int u) -> const bf16* {
    const int hcu = u >> 3, su = u & 7;
    return (su < 4) ? W1p + (hcu * 4 + su) * 8192
                    : W2p + ((((su >= 6) ? 16 : 0) + hcu * 2 + (su & 1))) * 8192;
  };
  // C = Aop @ Bop^T fragment step over one 64-k panel (kk=0..1), 16x16x32.
  auto mm = [&](const unsigned short* Abase, const unsigned short* Bbase,
                int arow0, int brow0, f32x4 (&acc)[4][4]) {
#pragma unroll
    for (int kk = 0; kk < 2; ++kk) {
      bf16x8 af[4], bfr[4];
#pragma unroll
      for (int x = 0; x < 4; ++x) {
        const int row = arow0 + x * 16 + l16;
        const int c8 = (kk * 4 + quad) ^ (row & 7);
        af[x] = *(const bf16x8*)(Abase + row * 64 + c8 * 8);
      }
#pragma unroll
      for (int x = 0; x < 4; ++x) {
        const int row = brow0 + x * 16 + l16;
        const int c8 = (kk * 4 + quad) ^ (row & 7);
        bfr[x] = *(const bf16x8*)(Bbase + row * 64 + c8 * 8);
      }
#pragma unroll
      for (int a = 0; a < 4; ++a) {
#pragma unroll
        for (int b = 0; b < 4; ++b) {
          acc[a][b] = __builtin_amdgcn_mfma_f32_16x16x32_bf16(
              af[a], bfr[b], acc[a][b], 0, 0, 0);
        }
      }
    }
  };

  // prologue: A tile (64 KiB contiguous) + first W1 panel
  {
    const bf16* Ap = A + mtile * 32768;
#pragma unroll
    for (int c = 0; c < 16; ++c) {
      const int f = c * 256 + tid;
      async_ld16(Ap + f * 8, (char*)Ares + f * 16);
    }
    stageW(W1p, 0);
  }

  const f32x4 fz = {0.f, 0.f, 0.f, 0.f};
  f32x4 acc2a[4][4], acc2b[4][4];
#pragma unroll
  for (int a = 0; a < 4; ++a) {
#pragma unroll
    for (int b = 0; b < 4; ++b) { acc2a[a][b] = fz; acc2b[a][b] = fz; }
  }

#pragma unroll 1
  for (int hc = 0; hc < 8; ++hc) {
    f32x4 acc1[4][4];
#pragma unroll
    for (int a = 0; a < 4; ++a) {
#pragma unroll
      for (int b = 0; b < 4; ++b) acc1[a][b] = fz;
    }
    f32x4 b1v[4];
    // phase 1: acc1[hidden][m] over 4 K-panels (A-operand = W1 rows)
#pragma unroll
    for (int s = 0; s < 4; ++s) {
      const int t = hc * 8 + s;
      __syncthreads();
      stageW(wptr(t + 1), (t + 1) & 1);
      if (s == 2) {
#pragma unroll
        for (int x = 0; x < 4; ++x)
          b1v[x] = *(const f32x4*)(b1 + hc * 128 + wn * 64 + x * 16 + quad * 4);
      }
      mm(Wbuf + (t & 1) * 8192, Ares + s * 8192, wn * 64, wm * 64, acc1);
    }
    // gelu + pack P (rows = m, k = hidden local; 4 consecutive k per lane)
#pragma unroll
    for (int ht = 0; ht < 4; ++ht) {
#pragma unroll
      for (int mt = 0; mt < 4; ++mt) {
        const int m_l = wm * 64 + mt * 16 + l16;
        ushort4 pk;
#pragma unroll
        for (int r = 0; r < 4; ++r) {
          const float v = acc1[ht][mt][r] + b1v[ht][r];
          const float g = 0.5f * v * (1.0f + erff(v * 0.70710678118654752f));
          ((unsigned short*)&pk)[r] = bfbits(g);
        }
        const int c8p = (ht * 2 + (quad >> 1)) ^ (m_l & 7);
        *(ushort4*)(Pbuf + wn * 8192 + m_l * 64 + c8p * 8 + (quad & 1) * 4) = pk;
      }
    }
    // phase 2: out-tile accumulation, P (A-operand) x W2 (B-operand)
    {
      const int t = hc * 8 + 4;
      __syncthreads();
      stageW(wptr(t + 1), (t + 1) & 1);
      mm(Pbuf, Wbuf + (t & 1) * 8192, wm * 64, wn * 64, acc2a);
    }
    {
      const int t = hc * 8 + 5;
      __syncthreads();
      stageW(wptr(t + 1), (t + 1) & 1);
      mm(Pbuf + 8192, Wbuf + (t & 1) * 8192, wm * 64, wn * 64, acc2a);
    }
    {
      const int t = hc * 8 + 6;
      __syncthreads();
      stageW(wptr(t + 1), (t + 1) & 1);
      mm(Pbuf, Wbuf + (t & 1) * 8192, wm * 64, wn * 64, acc2b);
    }
    {
      const int t = hc * 8 + 7;
      __syncthreads();
      if (t + 1 < 64) stageW(wptr(t + 1), (t + 1) & 1);
      mm(Pbuf + 8192, Wbuf + (t & 1) * 8192, wm * 64, wn * 64, acc2b);
    }
  }

  // epilogue: out[m][j] += acc2 + b2[j]  (RMW, 64B-run coalesced)
  const long m0 = mtile * 128;
  float b2a[4], b2b[4];
#pragma unroll
  for (int nt = 0; nt < 4; ++nt) {
    b2a[nt] = b2[wn * 64 + nt * 16 + l16];
    b2b[nt] = b2[128 + wn * 64 + nt * 16 + l16];
  }
#pragma unroll
  for (int mt = 0; mt < 4; ++mt) {
#pragma unroll
    for (int nt = 0; nt < 4; ++nt) {
      const long mb = m0 + wm * 64 + mt * 16 + quad * 4;
      const int ja = wn * 64 + nt * 16 + l16;
#pragma unroll
      for (int r = 0; r < 4; ++r) {
        out[(mb + r) * 256 + ja] += acc2a[mt][nt][r] + b2a[nt];
        out[(mb + r) * 256 + ja + 128] += acc2b[mt][nt][r] + b2b[nt];
      }
    }
  }
}

// ---------------- fused window attention ------------------------------------
__global__ __launch_bounds__(256) void attn_kern(
    const bf16* __restrict__ Qb, const bf16* __restrict__ Kb,
    const bf16* __restrict__ Vtb, bf16* __restrict__ O) {
  __shared__ __align__(16) unsigned short P[4][64 * 72];
  __shared__ __align__(16) unsigned short Cw[4][64 * 72];
  const int lane = threadIdx.x & 63;
  const int wv = threadIdx.x >> 6;
  const int quad = lane >> 4, l16 = lane & 15;
  const long w = blockIdx.x;
  unsigned short* Pw = &P[wv][0];
  unsigned short* Cww = &Cw[wv][0];
  const float SC = 0.17677669529663689f;  // 1/sqrt(32)
  const f32x4 fz = {0.f, 0.f, 0.f, 0.f};

#pragma unroll 1
  for (int hi = 0; hi < 2; ++hi) {
    const int h = wv * 2 + hi;
    const bf16* qp = Qb + ((w * 8 + h) * 64) * 32;
    const bf16* kp = Kb + ((w * 8 + h) * 64) * 32;
    const bf16* vt = Vtb + ((w * 8 + h) * 32) * 64;

    bf16x8 qf[4], kf[4];
#pragma unroll
    for (int mt = 0; mt < 4; ++mt)
      qf[mt] = *(const bf16x8*)(qp + (mt * 16 + l16) * 32 + quad * 8);
#pragma unroll
    for (int nt = 0; nt < 4; ++nt)
      kf[nt] = *(const bf16x8*)(kp + (nt * 16 + l16) * 32 + quad * 8);

    f32x4 s[4][4];
#pragma unroll
    for (int a = 0; a < 4; ++a) {
#pragma unroll
      for (int b = 0; b < 4; ++b) s[a][b] = fz;
    }
#pragma unroll
    for (int mt = 0; mt < 4; ++mt) {
#pragma unroll
      for (int nt = 0; nt < 4; ++nt) {
        s[mt][nt] = __builtin_amdgcn_mfma_f32_16x16x32_bf16(qf[mt], kf[nt],
                                                            s[mt][nt], 0, 0, 0);
      }
    }

#pragma unroll
    for (int mt = 0; mt < 4; ++mt) {
#pragma unroll
      for (int r = 0; r < 4; ++r) {
        float a0 = s[mt][0][r] * SC, a1 = s[mt][1][r] * SC;
        float a2 = s[mt][2][r] * SC, a3 = s[mt][3][r] * SC;
        float mx = fmaxf(fmaxf(a0, a1), fmaxf(a2, a3));
#pragma unroll
        for (int off = 8; off > 0; off >>= 1) mx = fmaxf(mx, __shfl_xor(mx, off));
        a0 = __expf(a0 - mx); a1 = __expf(a1 - mx);
        a2 = __expf(a2 - mx); a3 = __expf(a3 - mx);
        float sm = a0 + a1 + a2 + a3;
#pragma unroll
        for (int off = 8; off > 0; off >>= 1) sm += __shfl_xor(sm, off);
        const float iv = 1.0f / sm;
        const int rp = (mt * 16 + quad * 4 + r) * 72;
        Pw[rp + l16]      = bfbits(a0 * iv);
        Pw[rp + 16 + l16] = bfbits(a1 * iv);
        Pw[rp + 32 + l16] = bfbits(a2 * iv);
        Pw[rp + 48 + l16] = bfbits(a3 * iv);
      }
    }

    bf16x8 vf[2][2];
#pragma unroll
    for (int kt = 0; kt < 2; ++kt) {
#pragma unroll
      for (int dt = 0; dt < 2; ++dt)
        vf[kt][dt] = *(const bf16x8*)(vt + (dt * 16 + l16) * 64 + kt * 32 + quad * 8);
    }
    f32x4 oa[4][2];
#pragma unroll
    for (int a = 0; a < 4; ++a) { oa[a][0] = fz; oa[a][1] = fz; }
#pragma unroll
    for (int mt = 0; mt < 4; ++mt) {
      const unsigned short* pr = Pw + (mt * 16 + l16) * 72 + quad * 8;
      const bf16x8 p0 = *(const bf16x8*)(pr);
      const bf16x8 p1 = *(const bf16x8*)(pr + 32);
#pragma unroll
      for (int dt = 0; dt < 2; ++dt) {
        oa[mt][dt] = __builtin_amdgcn_mfma_f32_16x16x32_bf16(p0, vf[0][dt], oa[mt][dt], 0, 0, 0);
        oa[mt][dt] = __builtin_amdgcn_mfma_f32_16x16x32_bf16(p1, vf[1][dt], oa[mt][dt], 0, 0, 0);
      }
    }

#pragma unroll
    for (int mt = 0; mt < 4; ++mt) {
#pragma unroll
      for (int dt = 0; dt < 2; ++dt) {
#pragma unroll
        for (int r = 0; r < 4; ++r) {
          const int m_l = mt * 16 + quad * 4 + r;
          const int j_l = hi * 32 + dt * 16 + l16;
          Cww[m_l * 72 + j_l] = bfbits(oa[mt][dt][r]);
        }
      }
    }
  }

  __syncthreads();
  const long tile = w >> 1;
  const int half = (int)(w & 1);
#pragma unroll
  for (int p = 0; p < 8; ++p) {
    const int u = p * 64 + lane;
    const int row = u >> 3, c8 = u & 7;
    const unsigned short* src = Cww + row * 72 + ((c8 ^ (row & 7)) * 8);
    unsigned short* dst = (unsigned short*)O +
        ((tile * 4 + wv) * 1024 + (half * 64 + row) * 8 + c8) * 8;
    *(u16x8*)dst = *(const u16x8*)src;
  }
}

// ---------------- launch -----------------------------------------------------
// Workspace budget: HARD CAP 256 MiB (peak = QKV phase, exactly 256 MiB).
extern "C" void kernel_launch(void* const* d_in, const int* in_sizes, int n_in,
                              void* d_out, int out_size, void* d_ws, size_t ws_size,
                              hipStream_t stream) {
  const float* x     = (const float*)d_in[0];
  const float* ln1g  = (const float*)d_in[1];
  const float* ln1b  = (const float*)d_in[2];
  const float* in_w  = (const float*)d_in[3];
  const float* in_b  = (const float*)d_in[4];
  const float* out_w = (const float*)d_in[5];
  const float* out_b = (const float*)d_in[6];
  const float* ln2g  = (const float*)d_in[7];
  const float* ln2b  = (const float*)d_in[8];
  const float* w1    = (const float*)d_in[9];
  const float* b1    = (const float*)d_in[10];
  const float* w2    = (const float*)d_in[11];
  const float* b2    = (const float*)d_in[12];
  float* out = (float*)d_out;

  char* ws = (char*)d_ws;
  const size_t MB = 1ull << 20;
  bf16* XW   = (bf16*)ws;                 // [0,64)
  bf16* Qb   = (bf16*)(ws + 64 * MB);     // [64,128)
  bf16* Kb   = (bf16*)(ws + 128 * MB);    // [128,192)
  bf16* Vtb  = (bf16*)(ws + 192 * MB);    // [192,256)
  bf16* WB   = (bf16*)(ws + 64 * MB);     // deferred weights (over dead Qb)
  bf16* Wo   = WB;                        // 65536 el
  bf16* W1c  = WB + 65536;                // 262144 el
  bf16* W2c  = WB + 327680;               // 262144 el
  bf16* Obuf = XW;
  bf16* Hbuf = XW;

  ln_kern<true><<<MTOK / 4, 256, 0, stream>>>(x, ln1g, ln1b, XW);
  gemm_db<4, EPI_QKV, true><<<dim3(6, MTOK / 128), 256, 0, stream>>>(
      XW, in_w, in_b, Qb, Kb, Vtb, nullptr, nullptr, nullptr);
  attn_kern<<<2048, 256, 0, stream>>>(Qb, Kb, Vtb, Obuf);
  cvt_w2<<<2304, 256, 0, stream>>>(out_w, w1, w2, WB);
  gemm_db<4, EPI_OUTPROJ, false><<<dim3(2, MTOK / 128), 256, 0, stream>>>(
      Obuf, Wo, out_b, nullptr, nullptr, nullptr, x, out, nullptr);
  ln_kern<false><<<MTOK / 4, 256, 0, stream>>>(out, ln2g, ln2b, Hbuf);
  mlp_fused<<<MTOK / 128, 256, 0, stream>>>(Hbuf, W1c, W2c, b1, b2, out);
}

// Round 5
// 763.024 us; speedup vs baseline: 1.0774x; 1.0774x over previous
//
#include <hip/hip_runtime.h>
#include <hip/hip_bf16.h>
#include <cstdint>

#define DEVINL __device__ __forceinline__

using bf16 = __hip_bfloat16;
typedef __bf16 bf16x8 __attribute__((ext_vector_type(8)));
typedef float f32x4 __attribute__((ext_vector_type(4)));
typedef unsigned short u16x8 __attribute__((ext_vector_type(8)));

static constexpr int MTOK = 131072;  // B*N tokens

DEVINL void async_ld16(const void* g, void* l) {
  __builtin_amdgcn_global_load_lds(
      (__attribute__((address_space(1))) void*)(g),
      (__attribute__((address_space(3))) void*)(l), 16, 0, 0);
}

DEVINL unsigned short bfbits(float v) {
  bf16 h = __float2bfloat16(v);
  return *reinterpret_cast<unsigned short*>(&h);
}

// Swizzle-packed panel layout for [rows x K] bf16 matrices:
// granule(16B) f = row*8 + (chunk ^ (row&7)), panels of 128x64 linear (16 KiB).
DEVINL long pkaddr(long m, int k, int KP) {
  const long tile = m >> 7;
  const int row = (int)(m & 127);
  const int panel = k >> 6;
  const int c8 = ((k & 63) >> 3) ^ (row & 7);
  return ((tile * KP + panel) * 1024 + row * 8 + c8) * 8 + (k & 7);
}

// ---------------- deferred weights fp32 -> packed bf16 ----------------------
__global__ __launch_bounds__(256) void cvt_w2(
    const float* __restrict__ ow, const float* __restrict__ w1,
    const float* __restrict__ w2, bf16* __restrict__ out) {
  int i = blockIdx.x * 256 + threadIdx.x;
  float v; long base; int n, k, KP;
  if (i < 65536)        { v = ow[i]; base = 0;      n = i >> 8;  k = i & 255;  KP = 4; }
  else if (i < 327680)  { int j = i - 65536;  v = w1[j]; base = 65536;  n = j >> 8;  k = j & 255;  KP = 4; }
  else                  { int j = i - 327680; v = w2[j]; base = 327680; n = j >> 10; k = j & 1023; KP = 16; }
  out[base + pkaddr(n, k, KP)] = __float2bfloat16(v);
}

// ---------------- LayerNorm (+optional window partition), fp32 -> packed ----
template <bool REMAP>
__global__ __launch_bounds__(256) void ln_kern(
    const float* __restrict__ x, const float* __restrict__ gw,
    const float* __restrict__ bw, bf16* __restrict__ out) {
  const int lane = threadIdx.x & 63;
  const int wv = threadIdx.x >> 6;
  const long tok = (long)blockIdx.x * 4 + wv;
  const float4 v = *(const float4*)(x + tok * 256 + lane * 4);
  float s = v.x + v.y + v.z + v.w;
#pragma unroll
  for (int off = 32; off > 0; off >>= 1) s += __shfl_xor(s, off);
  const float mean = s * (1.0f / 256.0f);
  const float dx = v.x - mean, dy = v.y - mean, dz = v.z - mean, dw = v.w - mean;
  float q = dx * dx + dy * dy + dz * dz + dw * dw;
#pragma unroll
  for (int off = 32; off > 0; off >>= 1) q += __shfl_xor(q, off);
  const float inv = rsqrtf(q * (1.0f / 256.0f) + 1e-5f);
  long m;
  if (REMAP) {
    const int b = (int)(tok >> 14);
    const int n = (int)(tok & 16383);
    const int row = n >> 7, col = n & 127;
    const int w = b * 256 + (row >> 3) * 16 + (col >> 3);
    const int t = (row & 7) * 8 + (col & 7);
    m = (long)w * 64 + t;
  } else {
    m = tok;
  }
  const float4 g = *(const float4*)(gw + lane * 4);
  const float4 bb = *(const float4*)(bw + lane * 4);
  ushort4 o;
  o.x = bfbits(dx * inv * g.x + bb.x);
  o.y = bfbits(dy * inv * g.y + bb.y);
  o.z = bfbits(dz * inv * g.z + bb.z);
  o.w = bfbits(dw * inv * g.w + bb.w);
  *(ushort4*)((unsigned short*)out + pkaddr(m, lane * 4, 4)) = o;
}

// ---------------- GEMM: C = A @ B^T (packed A, packed/fp32 B, +epilogue) ----
enum { EPI_QKV = 0, EPI_OUTPROJ = 1 };

template <int KP, int EPI, bool BF32>
__global__ __launch_bounds__(256) void gemm_db(
    const bf16* __restrict__ A, const void* __restrict__ Bw,
    const float* __restrict__ bias,
    bf16* __restrict__ oQ, bf16* __restrict__ oK, bf16* __restrict__ oV,
    const float* __restrict__ resid, float* __restrict__ of32) {
  __shared__ __align__(16) unsigned short smem[32768];  // 64 KiB
  const int tid = threadIdx.x;
  const int lane = tid & 63, wv = tid >> 6;
  const int quad = lane >> 4, l16 = lane & 15;
  const int wm = wv >> 1, wn = wv & 1;
  // T1 XCD-chunked swizzle (bijective; nwg divisible by 8)
  const int gx = gridDim.x;
  const int nwg = gx * gridDim.y;
  const int orig = blockIdx.x + gx * blockIdx.y;
  const int wg = (orig & 7) * (nwg >> 3) + (orig >> 3);
  const int ntile = wg % gx;
  const long mtile = wg / gx;
  const long m0 = mtile * 128;
  const int n0 = ntile * 128;

  const bf16* Bp = (const bf16*)Bw;
  const float* Bf = (const float*)Bw;
  float4 br[4][2];

  auto stageA = [&](int i, int buf) {
    const bf16* Apan = A + (mtile * KP + i) * 8192;
#pragma unroll
    for (int p = 0; p < 4; ++p) {
      const int f = p * 256 + tid;
      async_ld16(Apan + f * 8, (char*)smem + buf * 16384 + f * 16);
    }
  };
  auto stageB = [&](int i, int buf) {
    const bf16* Bpan = Bp + ((long)ntile * KP + i) * 8192;
#pragma unroll
    for (int p = 0; p < 4; ++p) {
      const int f = p * 256 + tid;
      async_ld16(Bpan + f * 8, (char*)smem + 32768 + buf * 16384 + f * 16);
    }
  };
  auto issueB = [&](int i) {
#pragma unroll
    for (int p = 0; p < 4; ++p) {
      const int f = p * 256 + tid, row = f >> 3;
      const int chunk = (f & 7) ^ (row & 7);
      const float* src = Bf + (long)(n0 + row) * 256 + i * 64 + chunk * 8;
      br[p][0] = *(const float4*)(src);
      br[p][1] = *(const float4*)(src + 4);
    }
  };
  auto writeB = [&](int buf) {
#pragma unroll
    for (int p = 0; p < 4; ++p) {
      const int f = p * 256 + tid;
      u16x8 o;
      o[0] = bfbits(br[p][0].x); o[1] = bfbits(br[p][0].y);
      o[2] = bfbits(br[p][0].z); o[3] = bfbits(br[p][0].w);
      o[4] = bfbits(br[p][1].x); o[5] = bfbits(br[p][1].y);
      o[6] = bfbits(br[p][1].z); o[7] = bfbits(br[p][1].w);
      *(u16x8*)((char*)smem + 32768 + buf * 16384 + f * 16) = o;
    }
  };

  const f32x4 fz = {0.f, 0.f, 0.f, 0.f};
  f32x4 acc[4][4];
#pragma unroll
  for (int a = 0; a < 4; ++a) {
#pragma unroll
    for (int b = 0; b < 4; ++b) acc[a][b] = fz;
  }

  if constexpr (BF32) { issueB(0); stageA(0, 0); }
  else                { stageA(0, 0); stageB(0, 0); }

#pragma unroll 1
  for (int i = 0; i < KP; ++i) {
    if constexpr (BF32) writeB(i & 1);
    __syncthreads();
    if (i + 1 < KP) {
      if constexpr (BF32) { issueB(i + 1); stageA(i + 1, (i + 1) & 1); }
      else                { stageA(i + 1, (i + 1) & 1); stageB(i + 1, (i + 1) & 1); }
    }
    const unsigned short* Asb = smem + (i & 1) * 8192;
    const unsigned short* Bsb = smem + 16384 + (i & 1) * 8192;
#pragma unroll
    for (int kk = 0; kk < 2; ++kk) {
      bf16x8 af[4], bfr[4];
#pragma unroll
      for (int mt = 0; mt < 4; ++mt) {
        const int row = wm * 64 + mt * 16 + l16;
        const int c8 = (kk * 4 + quad) ^ (row & 7);
        af[mt] = *(const bf16x8*)(Asb + row * 64 + c8 * 8);
      }
#pragma unroll
      for (int nt = 0; nt < 4; ++nt) {
        const int row = wn * 64 + nt * 16 + l16;
        const int c8 = (kk * 4 + quad) ^ (row & 7);
        bfr[nt] = *(const bf16x8*)(Bsb + row * 64 + c8 * 8);
      }
#pragma unroll
      for (int mt = 0; mt < 4; ++mt) {
#pragma unroll
        for (int nt = 0; nt < 4; ++nt) {
          acc[mt][nt] = __builtin_amdgcn_mfma_f32_16x16x32_bf16(
              af[mt], bfr[nt], acc[mt][nt], 0, 0, 0);
        }
      }
    }
  }

  // ---- epilogue. C/D layout col=lane&15, row=quad*4+reg [m89-verified] ----
  if constexpr (EPI == EPI_QKV) {
    const int region = n0 >> 8;
    float bj4[4];
#pragma unroll
    for (int nt = 0; nt < 4; ++nt) bj4[nt] = bias[n0 + wn * 64 + nt * 16 + l16];
    __syncthreads();
    if (region < 2) {
#pragma unroll
      for (int mt = 0; mt < 4; ++mt) {
#pragma unroll
        for (int nt = 0; nt < 4; ++nt) {
          const int j_l = wn * 64 + nt * 16 + l16;
#pragma unroll
          for (int r = 0; r < 4; ++r) {
            const int m_l = wm * 64 + mt * 16 + quad * 4 + r;
            smem[m_l * 136 + j_l] = bfbits(acc[mt][nt][r] + bj4[nt]);
          }
        }
      }
    } else {
#pragma unroll
      for (int mt = 0; mt < 4; ++mt) {
#pragma unroll
        for (int nt = 0; nt < 4; ++nt) {
          const int j_l = wn * 64 + nt * 16 + l16;
          const int m_b = wm * 64 + mt * 16 + quad * 4;
          ushort4 pk;
          pk.x = bfbits(acc[mt][nt][0] + bj4[nt]);
          pk.y = bfbits(acc[mt][nt][1] + bj4[nt]);
          pk.z = bfbits(acc[mt][nt][2] + bj4[nt]);
          pk.w = bfbits(acc[mt][nt][3] + bj4[nt]);
          *(ushort4*)(smem + j_l * 136 + m_b) = pk;
        }
      }
    }
    __syncthreads();
    bf16* dst0 = (region == 0) ? oQ : ((region == 1) ? oK : oV);
    const int hbase = (n0 >> 5) & 7;
    const long w0 = m0 >> 6;
    if (region < 2) {
#pragma unroll
      for (int p = 0; p < 8; ++p) {
        const int u = p * 256 + tid;
        const int c = u >> 8, rr = u & 255;
        const int t = rr >> 2, d0 = (rr & 3) * 8;
        const unsigned short* src = smem + ((c >> 2) * 64 + t) * 136 + (c & 3) * 32 + d0;
        const long hb = (w0 + (c >> 2)) * 8 + hbase + (c & 3);
        *(u16x8*)((unsigned short*)dst0 + (hb * 64 + t) * 32 + d0) = *(const u16x8*)src;
      }
    } else {
#pragma unroll
      for (int p = 0; p < 8; ++p) {
        const int u = p * 256 + tid;
        const int c = u >> 8, rr = u & 255;
        const int d = rr >> 3, t0 = (rr & 7) * 8;
        const unsigned short* src = smem + ((c & 3) * 32 + d) * 136 + (c >> 2) * 64 + t0;
        const long hb = (w0 + (c >> 2)) * 8 + hbase + (c & 3);
        *(u16x8*)((unsigned short*)dst0 + (hb * 32 + d) * 64 + t0) = *(const u16x8*)src;
      }
    }
  } else {
    // OUTPROJ fp32 epilogue (64B-run coalesced)
#pragma unroll
    for (int mt = 0; mt < 4; ++mt) {
#pragma unroll
      for (int nt = 0; nt < 4; ++nt) {
        const long mb = m0 + wm * 64 + mt * 16 + quad * 4;
        const int j = n0 + wn * 64 + nt * 16 + l16;
        const float bj = bias[j];
#pragma unroll
        for (int r = 0; r < 4; ++r) {
          const long m = mb + r;
          const float v = acc[mt][nt][r] + bj;
          const int w = (int)(m >> 6), t = (int)(m & 63);
          const int b = w >> 8, wi = w & 255;
          const int row = (wi >> 4) * 8 + (t >> 3);
          const int col = (wi & 15) * 8 + (t & 7);
          const long addr = ((long)b * 16384 + row * 128 + col) * 256 + j;
          of32[addr] = v + resid[addr];
        }
      }
    }
  }
}

// ---------------- fused MLP: out += GELU(A @ W1^T) @ W2^T + b2 --------------
// 64-row m-tile per block (grid 2048), 4 waves. Streaming double buffer
// (2 x 32 KiB): phase1 step = {W1 panel 16K | A half-panel 8K}, phase2 step =
// {W2 panel pair 32K}. P tile (64 x 128) in 16 KiB. LDS total 80 KiB ->
// 2 blocks/CU, 2 waves/SIMD: cross-block overlap hides the per-step
// vmcnt-drain that throttled the 1-wave/SIMD version (Occ 11.6%, R4).
// Phase1: wave owns 32 hidden rows (acc1[2][4]); phase2: wave owns 64-col
// n-strip (acc2[4][4]). 48 barriers/block (was 64).
__global__ __launch_bounds__(256, 2) void mlp_fused(
    const bf16* __restrict__ A, const bf16* __restrict__ W1p,
    const bf16* __restrict__ W2p, const float* __restrict__ b1,
    const float* __restrict__ b2, float* __restrict__ out) {
  __shared__ __align__(16) unsigned short smem[40960];  // 80 KiB
  unsigned short* Pbuf = smem + 32768;                  // 16 KiB (2 panels)
  const int tid = threadIdx.x;
  const int lane = tid & 63;
  const int wv = tid >> 6;
  const int quad = lane >> 4, l16 = lane & 15;
  const int bm = blockIdx.x;                       // 64-row tile index
  const bf16* Ab = A + (long)(bm >> 1) * 32768 + (bm & 1) * 4096;

  auto stage = [&](int g) {
    char* dst = (char*)smem + (g & 1) * 32768;
    const int hc = g / 6, t = g - hc * 6;
    if (t < 4) {
      const bf16* wp = W1p + (hc * 4 + t) * 8192;
#pragma unroll
      for (int c = 0; c < 4; ++c) {
        const int f = c * 256 + tid;
        async_ld16(wp + f * 8, dst + f * 16);
      }
      const bf16* ap = Ab + t * 8192;
#pragma unroll
      for (int c = 0; c < 2; ++c) {
        const int f = c * 256 + tid;
        async_ld16(ap + f * 8, dst + 16384 + f * 16);
      }
    } else {
#pragma unroll
      for (int rt = 0; rt < 2; ++rt) {
        const bf16* wp = W2p + (rt * 16 + hc * 2 + (t - 4)) * 8192;
#pragma unroll
        for (int c = 0; c < 4; ++c) {
          const int f = c * 256 + tid;
          async_ld16(wp + f * 8, dst + rt * 16384 + f * 16);
        }
      }
    }
  };

  const f32x4 fz = {0.f, 0.f, 0.f, 0.f};
  f32x4 acc2[4][4];
#pragma unroll
  for (int a = 0; a < 4; ++a) {
#pragma unroll
    for (int b = 0; b < 4; ++b) acc2[a][b] = fz;
  }

  stage(0);

#pragma unroll 1
  for (int hc = 0; hc < 8; ++hc) {
    f32x4 acc1[2][4];
#pragma unroll
    for (int a = 0; a < 2; ++a) {
#pragma unroll
      for (int b = 0; b < 4; ++b) acc1[a][b] = fz;
    }
    f32x4 b1v[2];
#pragma unroll
    for (int ht = 0; ht < 2; ++ht)
      b1v[ht] = *(const f32x4*)(b1 + hc * 128 + wv * 32 + ht * 16 + quad * 4);

    // phase 1: acc1[hidden][m], A-op = W1 rows, B-op = A rows
#pragma unroll
    for (int s = 0; s < 4; ++s) {
      const int g = hc * 6 + s;
      __syncthreads();
      stage(g + 1);
      const unsigned short* buf = smem + (g & 1) * 16384;
#pragma unroll
      for (int kk = 0; kk < 2; ++kk) {
        bf16x8 af[2], bfr[4];
#pragma unroll
        for (int x = 0; x < 2; ++x) {
          const int row = wv * 32 + x * 16 + l16;
          const int c8 = (kk * 4 + quad) ^ (row & 7);
          af[x] = *(const bf16x8*)(buf + row * 64 + c8 * 8);
        }
#pragma unroll
        for (int x = 0; x < 4; ++x) {
          const int row = x * 16 + l16;
          const int c8 = (kk * 4 + quad) ^ (row & 7);
          bfr[x] = *(const bf16x8*)(buf + 8192 + row * 64 + c8 * 8);
        }
#pragma unroll
        for (int a = 0; a < 2; ++a) {
#pragma unroll
          for (int b = 0; b < 4; ++b) {
            acc1[a][b] = __builtin_amdgcn_mfma_f32_16x16x32_bf16(
                af[a], bfr[b], acc1[a][b], 0, 0, 0);
          }
        }
      }
    }

    // gelu + pack P: value at (m = mt*16+l16, k0 = wv*32+ht*16+quad*4)
#pragma unroll
    for (int ht = 0; ht < 2; ++ht) {
      const int k0 = wv * 32 + ht * 16 + quad * 4;
      const int panel = k0 >> 6, kin = k0 & 63;
#pragma unroll
      for (int mt = 0; mt < 4; ++mt) {
        const int m = mt * 16 + l16;
        ushort4 pk;
#pragma unroll
        for (int r = 0; r < 4; ++r) {
          const float v = acc1[ht][mt][r] + b1v[ht][r];
          const float g = 0.5f * v * (1.0f + erff(v * 0.70710678118654752f));
          ((unsigned short*)&pk)[r] = bfbits(g);
        }
        const int c8 = (kin >> 3) ^ (m & 7);
        *(ushort4*)(Pbuf + panel * 4096 + m * 64 + c8 * 8 + (kin & 7)) = pk;
      }
    }

    // phase 2: acc2 += P @ W2^T (wave n-strip = wv*64..+64)
#pragma unroll
    for (int kp = 0; kp < 2; ++kp) {
      const int g = hc * 6 + 4 + kp;
      __syncthreads();
      if (g + 1 < 48) stage(g + 1);
      const unsigned short* buf = smem + (g & 1) * 16384;
      const unsigned short* pp = Pbuf + kp * 4096;
#pragma unroll
      for (int kk = 0; kk < 2; ++kk) {
        bf16x8 af[4], bfr[4];
#pragma unroll
        for (int x = 0; x < 4; ++x) {
          const int row = x * 16 + l16;
          const int c8 = (kk * 4 + quad) ^ (row & 7);
          af[x] = *(const bf16x8*)(pp + row * 64 + c8 * 8);
        }
#pragma unroll
        for (int x = 0; x < 4; ++x) {
          const int row = (wv & 1) * 64 + x * 16 + l16;
          const int c8 = (kk * 4 + quad) ^ (row & 7);
          bfr[x] = *(const bf16x8*)(buf + (wv >> 1) * 8192 + row * 64 + c8 * 8);
        }
#pragma unroll
        for (int a = 0; a < 4; ++a) {
#pragma unroll
          for (int b = 0; b < 4; ++b) {
            acc2[a][b] = __builtin_amdgcn_mfma_f32_16x16x32_bf16(
                af[a], bfr[b], acc2[a][b], 0, 0, 0);
          }
        }
      }
    }
  }

  // epilogue: out[m][n] += acc2 + b2[n]  (RMW, 64B-run coalesced)
  const long m0 = (long)bm * 64;
  float b2v[4];
#pragma unroll
  for (int nt = 0; nt < 4; ++nt) b2v[nt] = b2[wv * 64 + nt * 16 + l16];
#pragma unroll
  for (int mt = 0; mt < 4; ++mt) {
#pragma unroll
    for (int nt = 0; nt < 4; ++nt) {
      const int n = wv * 64 + nt * 16 + l16;
#pragma unroll
      for (int r = 0; r < 4; ++r) {
        const long m = m0 + mt * 16 + quad * 4 + r;
        out[m * 256 + n] += acc2[mt][nt][r] + b2v[nt];
      }
    }
  }
}

// ---------------- fused window attention ------------------------------------
__global__ __launch_bounds__(256) void attn_kern(
    const bf16* __restrict__ Qb, const bf16* __restrict__ Kb,
    const bf16* __restrict__ Vtb, bf16* __restrict__ O) {
  __shared__ __align__(16) unsigned short P[4][64 * 72];
  __shared__ __align__(16) unsigned short Cw[4][64 * 72];
  const int lane = threadIdx.x & 63;
  const int wv = threadIdx.x >> 6;
  const int quad = lane >> 4, l16 = lane & 15;
  const long w = blockIdx.x;
  unsigned short* Pw = &P[wv][0];
  unsigned short* Cww = &Cw[wv][0];
  const float SC = 0.17677669529663689f;  // 1/sqrt(32)
  const f32x4 fz = {0.f, 0.f, 0.f, 0.f};

#pragma unroll 1
  for (int hi = 0; hi < 2; ++hi) {
    const int h = wv * 2 + hi;
    const bf16* qp = Qb + ((w * 8 + h) * 64) * 32;
    const bf16* kp = Kb + ((w * 8 + h) * 64) * 32;
    const bf16* vt = Vtb + ((w * 8 + h) * 32) * 64;

    bf16x8 qf[4], kf[4];
#pragma unroll
    for (int mt = 0; mt < 4; ++mt)
      qf[mt] = *(const bf16x8*)(qp + (mt * 16 + l16) * 32 + quad * 8);
#pragma unroll
    for (int nt = 0; nt < 4; ++nt)
      kf[nt] = *(const bf16x8*)(kp + (nt * 16 + l16) * 32 + quad * 8);

    f32x4 s[4][4];
#pragma unroll
    for (int a = 0; a < 4; ++a) {
#pragma unroll
      for (int b = 0; b < 4; ++b) s[a][b] = fz;
    }
#pragma unroll
    for (int mt = 0; mt < 4; ++mt) {
#pragma unroll
      for (int nt = 0; nt < 4; ++nt) {
        s[mt][nt] = __builtin_amdgcn_mfma_f32_16x16x32_bf16(qf[mt], kf[nt],
                                                            s[mt][nt], 0, 0, 0);
      }
    }

#pragma unroll
    for (int mt = 0; mt < 4; ++mt) {
#pragma unroll
      for (int r = 0; r < 4; ++r) {
        float a0 = s[mt][0][r] * SC, a1 = s[mt][1][r] * SC;
        float a2 = s[mt][2][r] * SC, a3 = s[mt][3][r] * SC;
        float mx = fmaxf(fmaxf(a0, a1), fmaxf(a2, a3));
#pragma unroll
        for (int off = 8; off > 0; off >>= 1) mx = fmaxf(mx, __shfl_xor(mx, off));
        a0 = __expf(a0 - mx); a1 = __expf(a1 - mx);
        a2 = __expf(a2 - mx); a3 = __expf(a3 - mx);
        float sm = a0 + a1 + a2 + a3;
#pragma unroll
        for (int off = 8; off > 0; off >>= 1) sm += __shfl_xor(sm, off);
        const float iv = 1.0f / sm;
        const int rp = (mt * 16 + quad * 4 + r) * 72;
        Pw[rp + l16]      = bfbits(a0 * iv);
        Pw[rp + 16 + l16] = bfbits(a1 * iv);
        Pw[rp + 32 + l16] = bfbits(a2 * iv);
        Pw[rp + 48 + l16] = bfbits(a3 * iv);
      }
    }

    bf16x8 vf[2][2];
#pragma unroll
    for (int kt = 0; kt < 2; ++kt) {
#pragma unroll
      for (int dt = 0; dt < 2; ++dt)
        vf[kt][dt] = *(const bf16x8*)(vt + (dt * 16 + l16) * 64 + kt * 32 + quad * 8);
    }
    f32x4 oa[4][2];
#pragma unroll
    for (int a = 0; a < 4; ++a) { oa[a][0] = fz; oa[a][1] = fz; }
#pragma unroll
    for (int mt = 0; mt < 4; ++mt) {
      const unsigned short* pr = Pw + (mt * 16 + l16) * 72 + quad * 8;
      const bf16x8 p0 = *(const bf16x8*)(pr);
      const bf16x8 p1 = *(const bf16x8*)(pr + 32);
#pragma unroll
      for (int dt = 0; dt < 2; ++dt) {
        oa[mt][dt] = __builtin_amdgcn_mfma_f32_16x16x32_bf16(p0, vf[0][dt], oa[mt][dt], 0, 0, 0);
        oa[mt][dt] = __builtin_amdgcn_mfma_f32_16x16x32_bf16(p1, vf[1][dt], oa[mt][dt], 0, 0, 0);
      }
    }

#pragma unroll
    for (int mt = 0; mt < 4; ++mt) {
#pragma unroll
      for (int dt = 0; dt < 2; ++dt) {
#pragma unroll
        for (int r = 0; r < 4; ++r) {
          const int m_l = mt * 16 + quad * 4 + r;
          const int j_l = hi * 32 + dt * 16 + l16;
          Cww[m_l * 72 + j_l] = bfbits(oa[mt][dt][r]);
        }
      }
    }
  }

  __syncthreads();
  const long tile = w >> 1;
  const int half = (int)(w & 1);
#pragma unroll
  for (int p = 0; p < 8; ++p) {
    const int u = p * 64 + lane;
    const int row = u >> 3, c8 = u & 7;
    const unsigned short* src = Cww + row * 72 + ((c8 ^ (row & 7)) * 8);
    unsigned short* dst = (unsigned short*)O +
        ((tile * 4 + wv) * 1024 + (half * 64 + row) * 8 + c8) * 8;
    *(u16x8*)dst = *(const u16x8*)src;
  }
}

// ---------------- launch -----------------------------------------------------
// Workspace budget: HARD CAP 256 MiB (peak = QKV phase, exactly 256 MiB).
extern "C" void kernel_launch(void* const* d_in, const int* in_sizes, int n_in,
                              void* d_out, int out_size, void* d_ws, size_t ws_size,
                              hipStream_t stream) {
  const float* x     = (const float*)d_in[0];
  const float* ln1g  = (const float*)d_in[1];
  const float* ln1b  = (const float*)d_in[2];
  const float* in_w  = (const float*)d_in[3];
  const float* in_b  = (const float*)d_in[4];
  const float* out_w = (const float*)d_in[5];
  const float* out_b = (const float*)d_in[6];
  const float* ln2g  = (const float*)d_in[7];
  const float* ln2b  = (const float*)d_in[8];
  const float* w1    = (const float*)d_in[9];
  const float* b1    = (const float*)d_in[10];
  const float* w2    = (const float*)d_in[11];
  const float* b2    = (const float*)d_in[12];
  float* out = (float*)d_out;

  char* ws = (char*)d_ws;
  const size_t MB = 1ull << 20;
  bf16* XW   = (bf16*)ws;                 // [0,64)
  bf16* Qb   = (bf16*)(ws + 64 * MB);     // [64,128)
  bf16* Kb   = (bf16*)(ws + 128 * MB);    // [128,192)
  bf16* Vtb  = (bf16*)(ws + 192 * MB);    // [192,256)
  bf16* WB   = (bf16*)(ws + 64 * MB);     // deferred weights (over dead Qb)
  bf16* Wo   = WB;                        // 65536 el
  bf16* W1c  = WB + 65536;                // 262144 el
  bf16* W2c  = WB + 327680;               // 262144 el
  bf16* Obuf = XW;
  bf16* Hbuf = XW;

  ln_kern<true><<<MTOK / 4, 256, 0, stream>>>(x, ln1g, ln1b, XW);
  gemm_db<4, EPI_QKV, true><<<dim3(6, MTOK / 128), 256, 0, stream>>>(
      XW, in_w, in_b, Qb, Kb, Vtb, nullptr, nullptr);
  attn_kern<<<2048, 256, 0, stream>>>(Qb, Kb, Vtb, Obuf);
  cvt_w2<<<2304, 256, 0, stream>>>(out_w, w1, w2, WB);
  gemm_db<4, EPI_OUTPROJ, false><<<dim3(2, MTOK / 128), 256, 0, stream>>>(
      Obuf, Wo, out_b, nullptr, nullptr, nullptr, x, out);
  ln_kern<false><<<MTOK / 4, 256, 0, stream>>>(out, ln2g, ln2b, Hbuf);
  mlp_fused<<<MTOK / 64, 256, 0, stream>>>(Hbuf, W1c, W2c, b1, b2, out);
}